// Round 2
// baseline (256.498 us; speedup 1.0000x reference)
//
#include <hip/hip_runtime.h>
#include <math.h>

#define NSTEP 10

// ---- fast atan2: Hastings poly, max err ~1e-4 rad (rot terms are <0.01% of loss) ----
__device__ __forceinline__ float fast_atan2f(float y, float x) {
    float ax = fabsf(x), ay = fabsf(y);
    float mx = fmaxf(ax, ay);
    float mn = fminf(ax, ay);
    float a = mn * __builtin_amdgcn_rcpf(fmaxf(mx, 1e-38f));
    float s = a * a;
    float r = fmaf(s, fmaf(s, fmaf(s, fmaf(s, 0.0208351f, -0.085133f),
                                   0.180141f), -0.3302995f), 0.9998660f) * a;
    if (ay > ax) r = 1.57079632679f - r;
    if (x < 0.0f) r = 3.14159265359f - r;
    return copysignf(r, y);
}

__device__ __forceinline__ void euler2mat(const float e[3], float R[9]) {
    float sx, cx, sy, cy, sz, cz;
    __sincosf(e[0], &sx, &cx);
    __sincosf(e[1], &sy, &cy);
    __sincosf(e[2], &sz, &cz);
    R[0] = cz * cy; R[1] = cz * sy * sx - sz * cx; R[2] = cz * sy * cx + sz * sx;
    R[3] = sz * cy; R[4] = sz * sy * sx + cz * cx; R[5] = sz * sy * cx - cz * sx;
    R[6] = -sy;     R[7] = cy * sx;                R[8] = cy * cx;
}

__device__ __forceinline__ void mat2euler(const float M[9], float e[3]) {
    float sy = sqrtf(fmaf(M[0], M[0], M[3] * M[3]));
    bool sing = sy < 1e-6f;
    float a0 = sing ? -M[5] : M[7];
    float a1 = sing ?  M[4] : M[8];
    e[0] = fast_atan2f(a0, a1);
    e[1] = fast_atan2f(-M[6], sy);
    e[2] = sing ? 0.0f : fast_atan2f(M[3], M[0]);
}

__global__ __launch_bounds__(256, 5) void cycle_loss_main(
    const float* __restrict__ pred, const float* __restrict__ gt,
    float* __restrict__ partial, int batch)
{
    int idx = blockIdx.x * blockDim.x + threadIdx.x;
    float acc = 0.0f;
    if (idx < batch) {
        const float4* p4 = reinterpret_cast<const float4*>(pred + (size_t)idx * 60);
        const float4* g4 = reinterpret_cast<const float4*>(gt   + (size_t)idx * 60);

        // streaming state (Q = R1 ⊙ P elementwise-cumprod; v,c,tprev for translation)
        float vp[3], vg[3], cp[3] = {0,0,0}, cg[3] = {0,0,0}, tpp[3], tpg[3];
        float Qp[9], Qg[9];

        #pragma unroll
        for (int c = 0; c < 5; ++c) {
            float4 Ap = p4[3*c], Bp = p4[3*c+1], Cp = p4[3*c+2];
            float4 Ag = g4[3*c], Bg = g4[3*c+1], Cg = g4[3*c+2];
            float t0p[3] = {Ap.x, Ap.y, Ap.z}, r0p[3] = {Ap.w, Bp.x, Bp.y};
            float t1p[3] = {Bp.z, Bp.w, Cp.x}, r1p[3] = {Cp.y, Cp.z, Cp.w};
            float t0g[3] = {Ag.x, Ag.y, Ag.z}, r0g[3] = {Ag.w, Bg.x, Bg.y};
            float t1g[3] = {Bg.z, Bg.w, Cg.x}, r1g[3] = {Cg.y, Cg.z, Cg.w};

            // ---------- translation: steps 2c and 2c+1 ----------
            if (c == 0) {
                #pragma unroll
                for (int k = 0; k < 3; ++k) {           // step 0: v = t0
                    vp[k] = t0p[k]; vg[k] = t0g[k];
                    float d = vp[k] - vg[k]; acc += d * d;
                }
                #pragma unroll
                for (int k = 0; k < 3; ++k) {           // step 1: v = 2v
                    vp[k] *= 2.0f; vg[k] *= 2.0f;
                    float d = vp[k] - vg[k]; acc += d * d;
                }
            } else {
                #pragma unroll
                for (int k = 0; k < 3; ++k) {           // step 2c: c += t_{2c-1}; v = 2v + c
                    cp[k] += tpp[k]; cg[k] += tpg[k];
                    vp[k] = fmaf(2.0f, vp[k], cp[k]);
                    vg[k] = fmaf(2.0f, vg[k], cg[k]);
                    float d = vp[k] - vg[k]; acc += d * d;
                }
                #pragma unroll
                for (int k = 0; k < 3; ++k) {           // step 2c+1: c += t_{2c}; v = 2v + c
                    cp[k] += t0p[k]; cg[k] += t0g[k];
                    vp[k] = fmaf(2.0f, vp[k], cp[k]);
                    vg[k] = fmaf(2.0f, vg[k], cg[k]);
                    float d = vp[k] - vg[k]; acc += d * d;
                }
            }
            #pragma unroll
            for (int k = 0; k < 3; ++k) { tpp[k] = t1p[k]; tpg[k] = t1g[k]; }

            // ---------- rotation: steps 2c and 2c+1 ----------
            float ep[3], eg[3];
            if (c == 0) {
                euler2mat(r0p, Qp);  euler2mat(r0g, Qg);     // Q = R0
                float Rtp[9], Rtg[9];
                euler2mat(r1p, Rtp); euler2mat(r1g, Rtg);    // Rt = R1
                mat2euler(Rtp, ep);  mat2euler(Rtg, eg);     // step 0: M = R1
                #pragma unroll
                for (int k = 0; k < 3; ++k) { float d = ep[k] - eg[k]; acc += d * d; }
                #pragma unroll
                for (int k = 0; k < 9; ++k) { Qp[k] *= Rtp[k]; Qg[k] *= Rtg[k]; }  // Q = R1⊙R0
                mat2euler(Qp, ep); mat2euler(Qg, eg);        // step 1
                #pragma unroll
                for (int k = 0; k < 3; ++k) { float d = ep[k] - eg[k]; acc += d * d; }
                #pragma unroll
                for (int k = 0; k < 9; ++k) { Qp[k] *= Rtp[k]; Qg[k] *= Rtg[k]; }  // Q ⊙= R1
            } else {
                mat2euler(Qp, ep); mat2euler(Qg, eg);        // step 2c
                #pragma unroll
                for (int k = 0; k < 3; ++k) { float d = ep[k] - eg[k]; acc += d * d; }
                {
                    float Rtp[9], Rtg[9];
                    euler2mat(r0p, Rtp); euler2mat(r0g, Rtg);
                    #pragma unroll
                    for (int k = 0; k < 9; ++k) { Qp[k] *= Rtp[k]; Qg[k] *= Rtg[k]; }
                }
                mat2euler(Qp, ep); mat2euler(Qg, eg);        // step 2c+1
                #pragma unroll
                for (int k = 0; k < 3; ++k) { float d = ep[k] - eg[k]; acc += d * d; }
                if (c < 4) {
                    float Rtp[9], Rtg[9];
                    euler2mat(r1p, Rtp); euler2mat(r1g, Rtg);
                    #pragma unroll
                    for (int k = 0; k < 9; ++k) { Qp[k] *= Rtp[k]; Qg[k] *= Rtg[k]; }
                }
            }
        }
    }

    // ---- reduction: wave shuffle -> LDS -> one float partial per block ----
    int lane = threadIdx.x & 63;
    int wid  = threadIdx.x >> 6;
    #pragma unroll
    for (int off = 32; off > 0; off >>= 1)
        acc += __shfl_down(acc, off, 64);
    __shared__ float warp_s[4];
    if (lane == 0) warp_s[wid] = acc;
    __syncthreads();
    if (threadIdx.x == 0)
        partial[blockIdx.x] = warp_s[0] + warp_s[1] + warp_s[2] + warp_s[3];
}

__global__ __launch_bounds__(256) void cycle_loss_fin(
    const float* __restrict__ partial, float* __restrict__ out,
    int nblocks, float inv)
{
    int t = threadIdx.x;
    float s = 0.0f;
    for (int i = t; i < nblocks; i += 256) s += partial[i];
    int lane = t & 63, wid = t >> 6;
    #pragma unroll
    for (int off = 32; off > 0; off >>= 1)
        s += __shfl_down(s, off, 64);
    __shared__ float warp_s[4];
    if (lane == 0) warp_s[wid] = s;
    __syncthreads();
    if (t == 0)
        out[0] = (warp_s[0] + warp_s[1] + warp_s[2] + warp_s[3]) * inv;
}

extern "C" void kernel_launch(void* const* d_in, const int* in_sizes, int n_in,
                              void* d_out, int out_size, void* d_ws, size_t ws_size,
                              hipStream_t stream) {
    const float* pred = (const float*)d_in[0];
    const float* gt   = (const float*)d_in[1];
    int batch = in_sizes[0] / 60;
    float* partial = (float*)d_ws;

    const int threads = 256;
    const int blocks = (batch + threads - 1) / threads;
    cycle_loss_main<<<blocks, threads, 0, stream>>>(pred, gt, partial, batch);

    double inv = 1.0 / (60.0 * (double)batch * (double)batch);
    cycle_loss_fin<<<1, threads, 0, stream>>>(partial, (float*)d_out, blocks, (float)inv);
}

// Round 3
// 155.331 us; speedup vs baseline: 1.6513x; 1.6513x over previous
//
#include <hip/hip_runtime.h>
#include <math.h>

#define NSTEP 10

// ---- fast atan2: Hastings poly, max err ~1e-4 rad (rot terms are <1e-9 of loss) ----
__device__ __forceinline__ float fast_atan2f(float y, float x) {
    float ax = fabsf(x), ay = fabsf(y);
    float mx = fmaxf(ax, ay);
    float mn = fminf(ax, ay);
    float a = mn * __builtin_amdgcn_rcpf(fmaxf(mx, 1e-38f));
    float s = a * a;
    float r = fmaf(s, fmaf(s, fmaf(s, fmaf(s, 0.0208351f, -0.085133f),
                                   0.180141f), -0.3302995f), 0.9998660f) * a;
    if (ay > ax) r = 1.57079632679f - r;
    if (x < 0.0f) r = 3.14159265359f - r;
    return copysignf(r, y);
}

__device__ __forceinline__ void euler2mat(float x, float y, float z, float R[9]) {
    float sx, cx, sy, cy, sz, cz;
    __sincosf(x, &sx, &cx);
    __sincosf(y, &sy, &cy);
    __sincosf(z, &sz, &cz);
    R[0] = cz * cy; R[1] = cz * sy * sx - sz * cx; R[2] = cz * sy * cx + sz * sx;
    R[3] = sz * cy; R[4] = sz * sy * sx + cz * cx; R[5] = sz * sy * cx - cz * sx;
    R[6] = -sy;     R[7] = cy * sx;                R[8] = cy * cx;
}

// emit one cycle element: diff against partner lane (pred<->gt), accumulate d^2
__device__ __forceinline__ void emit(float v, float& acc) {
    float d = v - __shfl_xor(v, 1, 64);
    acc = fmaf(d, d, acc);
}

__device__ __forceinline__ void emit_euler(const float M[9], float& acc) {
    float sy = sqrtf(fmaf(M[0], M[0], M[3] * M[3]));
    bool sing = sy < 1e-6f;
    float a0 = sing ? -M[5] : M[7];
    float a1 = sing ?  M[4] : M[8];
    emit(fast_atan2f(a0, a1), acc);
    emit(fast_atan2f(-M[6], sy), acc);
    emit(sing ? 0.0f : fast_atan2f(M[3], M[0]), acc);
}

__global__ __launch_bounds__(256) void cycle_loss_main(
    const float* __restrict__ pred, const float* __restrict__ gt,
    float* __restrict__ partial, int batch)
{
    int gid = blockIdx.x * blockDim.x + threadIdx.x;
    int row = gid >> 1;
    float acc = 0.0f;
    if (row < batch) {
        const float* src = (gid & 1) ? gt : pred;
        const float4* s4 = reinterpret_cast<const float4*>(src + (size_t)row * 60);

        // persistent chain state
        float v[3], cac[3] = {0,0,0}, tprev[3];
        float Q[9];

        // ---------------- chunk 0 (steps 0,1) ----------------
        float4 A = s4[0], B = s4[1], C = s4[2];
        float4 nA = s4[3], nB = s4[4], nC = s4[5];   // prefetch chunk 1

        // translation step 0: v = t0
        v[0] = A.x; v[1] = A.y; v[2] = A.z;
        emit(v[0], acc); emit(v[1], acc); emit(v[2], acc);
        // translation step 1: v = 2v
        #pragma unroll
        for (int k = 0; k < 3; ++k) { v[k] *= 2.0f; emit(v[k], acc); }
        tprev[0] = B.z; tprev[1] = B.w; tprev[2] = C.x;

        // rotation: Q starts as R0; R1 cached this chunk only
        {
            float R1[9];
            euler2mat(A.w, B.x, B.y, Q);        // Q = R0
            euler2mat(C.y, C.z, C.w, R1);       // R1
            emit_euler(R1, acc);                // step 0: M = R1
            #pragma unroll
            for (int k = 0; k < 9; ++k) Q[k] *= R1[k];   // Q = R1 (.) R0
            emit_euler(Q, acc);                 // step 1
            #pragma unroll
            for (int k = 0; k < 9; ++k) Q[k] *= R1[k];   // fold in R1 for P_2
        }

        // ---------------- chunks 1..4 (steps 2c, 2c+1) ----------------
        #pragma unroll 1
        for (int c = 1; c < 5; ++c) {
            A = nA; B = nB; C = nC;
            if (c < 4) { nA = s4[3*c+3]; nB = s4[3*c+4]; nC = s4[3*c+5]; }

            // translation step 2c: cac += t_{2c-1}; v = 2v + cac
            cac[0] += tprev[0]; cac[1] += tprev[1]; cac[2] += tprev[2];
            #pragma unroll
            for (int k = 0; k < 3; ++k) { v[k] = fmaf(2.0f, v[k], cac[k]); emit(v[k], acc); }
            // translation step 2c+1: cac += t_{2c}; v = 2v + cac
            cac[0] += A.x; cac[1] += A.y; cac[2] += A.z;
            #pragma unroll
            for (int k = 0; k < 3; ++k) { v[k] = fmaf(2.0f, v[k], cac[k]); emit(v[k], acc); }
            tprev[0] = B.z; tprev[1] = B.w; tprev[2] = C.x;

            // rotation step 2c: M = Q
            emit_euler(Q, acc);
            {
                float R[9];
                euler2mat(A.w, B.x, B.y, R);    // R_{2c}
                #pragma unroll
                for (int k = 0; k < 9; ++k) Q[k] *= R[k];
            }
            // rotation step 2c+1
            emit_euler(Q, acc);
            {
                float R[9];
                euler2mat(C.y, C.z, C.w, R);    // R_{2c+1} (last one wasted, keeps body uniform)
                #pragma unroll
                for (int k = 0; k < 9; ++k) Q[k] *= R[k];
            }
        }
    }

    // ---- reduction: wave shuffle -> LDS -> one float partial per block ----
    int lane = threadIdx.x & 63;
    int wid  = threadIdx.x >> 6;
    #pragma unroll
    for (int off = 32; off > 0; off >>= 1)
        acc += __shfl_down(acc, off, 64);
    __shared__ float warp_s[4];
    if (lane == 0) warp_s[wid] = acc;
    __syncthreads();
    if (threadIdx.x == 0)
        partial[blockIdx.x] = warp_s[0] + warp_s[1] + warp_s[2] + warp_s[3];
}

__global__ __launch_bounds__(256) void cycle_loss_fin(
    const float* __restrict__ partial, float* __restrict__ out,
    int nblocks, float inv)
{
    int t = threadIdx.x;
    float s = 0.0f;
    for (int i = t; i < nblocks; i += 256) s += partial[i];
    int lane = t & 63, wid = t >> 6;
    #pragma unroll
    for (int off = 32; off > 0; off >>= 1)
        s += __shfl_down(s, off, 64);
    __shared__ float warp_s[4];
    if (lane == 0) warp_s[wid] = s;
    __syncthreads();
    if (t == 0)
        out[0] = (warp_s[0] + warp_s[1] + warp_s[2] + warp_s[3]) * inv;
}

extern "C" void kernel_launch(void* const* d_in, const int* in_sizes, int n_in,
                              void* d_out, int out_size, void* d_ws, size_t ws_size,
                              hipStream_t stream) {
    const float* pred = (const float*)d_in[0];
    const float* gt   = (const float*)d_in[1];
    int batch = in_sizes[0] / 60;
    float* partial = (float*)d_ws;

    const int threads = 256;
    const int blocks = (2 * batch + threads - 1) / threads;
    cycle_loss_main<<<blocks, threads, 0, stream>>>(pred, gt, partial, batch);

    // each d^2 counted twice (both lanes of a pair) -> extra 0.5
    double inv = 0.5 / (60.0 * (double)batch * (double)batch);
    cycle_loss_fin<<<1, threads, 0, stream>>>(partial, (float*)d_out, blocks, (float)inv);
}

// Round 4
// 145.186 us; speedup vs baseline: 1.7667x; 1.0699x over previous
//
#include <hip/hip_runtime.h>
#include <math.h>

#define NSTEP 10
#define ROWS_PER_BLOCK 128
#define ROW_STRIDE 61                      // 60 + 1 pad: 32 lane-pairs hit 32 distinct banks
#define HALF_OFF (ROWS_PER_BLOCK * ROW_STRIDE)   // 7808, ≡ 0 mod 32 → pred/gt pair is 2-way (free)

// ---- fast atan2: Hastings poly, max err ~1e-4 rad (rot terms are <1e-9 of loss) ----
__device__ __forceinline__ float fast_atan2f(float y, float x) {
    float ax = fabsf(x), ay = fabsf(y);
    float mx = fmaxf(ax, ay);
    float mn = fminf(ax, ay);
    float a = mn * __builtin_amdgcn_rcpf(fmaxf(mx, 1e-38f));
    float s = a * a;
    float r = fmaf(s, fmaf(s, fmaf(s, fmaf(s, 0.0208351f, -0.085133f),
                                   0.180141f), -0.3302995f), 0.9998660f) * a;
    if (ay > ax) r = 1.57079632679f - r;
    if (x < 0.0f) r = 3.14159265359f - r;
    return copysignf(r, y);
}

__device__ __forceinline__ void euler2mat(float x, float y, float z, float R[9]) {
    float sx, cx, sy, cy, sz, cz;
    __sincosf(x, &sx, &cx);
    __sincosf(y, &sy, &cy);
    __sincosf(z, &sz, &cz);
    R[0] = cz * cy; R[1] = cz * sy * sx - sz * cx; R[2] = cz * sy * cx + sz * sx;
    R[3] = sz * cy; R[4] = sz * sy * sx + cz * cx; R[5] = sz * sy * cx - cz * sx;
    R[6] = -sy;     R[7] = cy * sx;                R[8] = cy * cx;
}

// diff against partner lane (pred<->gt) via DPP quad_perm [1,0,3,2] — pure VALU, no DS
__device__ __forceinline__ void emit(float v, float& acc) {
    int pi = __builtin_amdgcn_update_dpp(0, __float_as_int(v), 0xB1, 0xF, 0xF, true);
    float d = v - __int_as_float(pi);
    acc = fmaf(d, d, acc);
}

__device__ __forceinline__ void emit_euler(const float M[9], float& acc) {
    float sy = sqrtf(fmaf(M[0], M[0], M[3] * M[3]));
    bool sing = sy < 1e-6f;
    float a0 = sing ? -M[5] : M[7];
    float a1 = sing ?  M[4] : M[8];
    emit(fast_atan2f(a0, a1), acc);
    emit(fast_atan2f(-M[6], sy), acc);
    emit(sing ? 0.0f : fast_atan2f(M[3], M[0]), acc);
}

__global__ __launch_bounds__(256) void cycle_loss_main(
    const float* __restrict__ pred, const float* __restrict__ gt,
    float* __restrict__ partial, int batch)
{
    __shared__ float lds[2 * HALF_OFF];    // 62464 B
    const int tid = threadIdx.x;

    // ---------- staging: coalesced scalar loads, conflict-free padded LDS writes ----------
    // flat i in [0, 7680); lds index = row*61 + col = i + i/60
    {
        const size_t gbase = (size_t)blockIdx.x * (ROWS_PER_BLOCK * 60);
        #pragma unroll
        for (int it = 0; it < 30; ++it) {
            int i = tid + it * 256;
            int lidx = i + i / 60;
            lds[lidx]            = pred[gbase + i];
            lds[HALF_OFF + lidx] = gt[gbase + i];
        }
    }
    __syncthreads();

    // ---------- compute: thread = (local_row = tid>>1, array = tid&1) ----------
    float acc = 0.0f;
    {
        const float* row = lds + ((tid & 1) ? HALF_OFF : 0) + (tid >> 1) * ROW_STRIDE;

        float v[3], cac[3] = {0,0,0}, tprev[3];
        float Q[9];

        // ---- chunk 0 (steps 0,1): elements 0..11 ----
        float e0 = row[0], e1 = row[1], e2 = row[2], e3 = row[3];
        float e4 = row[4], e5 = row[5], e6 = row[6], e7 = row[7];
        float e8 = row[8], e9 = row[9], e10 = row[10], e11 = row[11];

        v[0] = e0; v[1] = e1; v[2] = e2;
        emit(v[0], acc); emit(v[1], acc); emit(v[2], acc);
        #pragma unroll
        for (int k = 0; k < 3; ++k) { v[k] *= 2.0f; emit(v[k], acc); }
        tprev[0] = e6; tprev[1] = e7; tprev[2] = e8;

        {
            float R1[9];
            euler2mat(e3, e4, e5, Q);          // Q = R0
            euler2mat(e9, e10, e11, R1);       // R1
            emit_euler(R1, acc);               // step 0: M = R1
            #pragma unroll
            for (int k = 0; k < 9; ++k) Q[k] *= R1[k];   // Q = R1 (.) R0
            emit_euler(Q, acc);                // step 1
            #pragma unroll
            for (int k = 0; k < 9; ++k) Q[k] *= R1[k];   // fold in R1 for P_2
        }

        // ---- chunks 1..4 (steps 2c, 2c+1): elements 12c..12c+11 ----
        #pragma unroll
        for (int c = 1; c < 5; ++c) {
            const float* rc = row + 12 * c;
            float f0 = rc[0], f1 = rc[1], f2 = rc[2], f3 = rc[3];
            float f4 = rc[4], f5 = rc[5], f6 = rc[6], f7 = rc[7];
            float f8 = rc[8], f9 = rc[9], f10 = rc[10], f11 = rc[11];

            // translation step 2c: cac += t_{2c-1}; v = 2v + cac
            cac[0] += tprev[0]; cac[1] += tprev[1]; cac[2] += tprev[2];
            #pragma unroll
            for (int k = 0; k < 3; ++k) { v[k] = fmaf(2.0f, v[k], cac[k]); emit(v[k], acc); }
            // translation step 2c+1: cac += t_{2c}; v = 2v + cac
            cac[0] += f0; cac[1] += f1; cac[2] += f2;
            #pragma unroll
            for (int k = 0; k < 3; ++k) { v[k] = fmaf(2.0f, v[k], cac[k]); emit(v[k], acc); }
            tprev[0] = f6; tprev[1] = f7; tprev[2] = f8;

            // rotation step 2c: M = Q
            emit_euler(Q, acc);
            {
                float R[9];
                euler2mat(f3, f4, f5, R);      // R_{2c}
                #pragma unroll
                for (int k = 0; k < 9; ++k) Q[k] *= R[k];
            }
            // rotation step 2c+1
            emit_euler(Q, acc);
            if (c < 4) {
                float R[9];
                euler2mat(f9, f10, f11, R);    // R_{2c+1}
                #pragma unroll
                for (int k = 0; k < 9; ++k) Q[k] *= R[k];
            }
        }
    }

    // ---- reduction: wave shuffle -> LDS -> one float partial per block ----
    int lane = tid & 63;
    int wid  = tid >> 6;
    #pragma unroll
    for (int off = 32; off > 0; off >>= 1)
        acc += __shfl_down(acc, off, 64);
    __shared__ float warp_s[4];
    if (lane == 0) warp_s[wid] = acc;
    __syncthreads();
    if (tid == 0)
        partial[blockIdx.x] = warp_s[0] + warp_s[1] + warp_s[2] + warp_s[3];
}

__global__ __launch_bounds__(256) void cycle_loss_fin(
    const float* __restrict__ partial, float* __restrict__ out,
    int nblocks, float inv)
{
    int t = threadIdx.x;
    float s = 0.0f;
    for (int i = t; i < nblocks; i += 256) s += partial[i];
    int lane = t & 63, wid = t >> 6;
    #pragma unroll
    for (int off = 32; off > 0; off >>= 1)
        s += __shfl_down(s, off, 64);
    __shared__ float warp_s[4];
    if (lane == 0) warp_s[wid] = s;
    __syncthreads();
    if (t == 0)
        out[0] = (warp_s[0] + warp_s[1] + warp_s[2] + warp_s[3]) * inv;
}

extern "C" void kernel_launch(void* const* d_in, const int* in_sizes, int n_in,
                              void* d_out, int out_size, void* d_ws, size_t ws_size,
                              hipStream_t stream) {
    const float* pred = (const float*)d_in[0];
    const float* gt   = (const float*)d_in[1];
    int batch = in_sizes[0] / 60;
    float* partial = (float*)d_ws;

    const int threads = 256;
    const int blocks = batch / ROWS_PER_BLOCK;   // 262144/128 = 2048, exact
    cycle_loss_main<<<blocks, threads, 0, stream>>>(pred, gt, partial, batch);

    // each d^2 counted twice (both lanes of a pair) -> extra 0.5
    double inv = 0.5 / (60.0 * (double)batch * (double)batch);
    cycle_loss_fin<<<1, threads, 0, stream>>>(partial, (float*)d_out, blocks, (float)inv);
}